// Round 5
// baseline (1553.786 us; speedup 1.0000x reference)
//
#include <hip/hip_runtime.h>
#include <hip/hip_fp16.h>
#include <cstdint>
#include <cstddef>

#define BB  256
#define TT  2048
#define KIN 182
#define HH  64
#define G3  192       // 3*H
#define CH  16        // timesteps per chunk (MFMA M)
#define NC  (TT/CH)   // 128 chunks
#define IGS 196       // padded fp32 row stride: producer stores 2-way (free)
#define NBLK (BB/2)   // 2 sequences per block

#define NFRAG (12*6*64)              // nt * kf * lane
#define WS_NEEDED ((size_t)NFRAG*16) // 73728 B of fp16 B-fragments

typedef _Float16 half8 __attribute__((ext_vector_type(8)));
typedef _Float16 h2v   __attribute__((ext_vector_type(2)));
typedef float    f32x4 __attribute__((ext_vector_type(4)));
typedef float    v2f   __attribute__((ext_vector_type(2)));

static __device__ __forceinline__ float dot2(h2v a, h2v b, float c) {
#if __has_builtin(__builtin_amdgcn_fdot2)
    return __builtin_amdgcn_fdot2(a, b, c, false);   // builtin: compiler schedules
#else
    return c + (float)a[0] * (float)b[0] + (float)a[1] * (float)b[1];
#endif
}

// ---------------------------------------------------------------------------
// One-time pre-pack: W_ih -> fp16 MFMA B-fragments in d_ws (same as round 4).
// ---------------------------------------------------------------------------
__global__ void pack_wih(const float* __restrict__ wih, _Float16* __restrict__ wsB) {
    int idx = blockIdx.x * 256 + threadIdx.x;
    if (idx >= NFRAG) return;
    int lane = idx & 63;
    int kf   = (idx >> 6) % 6;
    int nt   = idx / (6 * 64);
    int col  = lane & 15, kq = lane >> 4;
    int n = nt * 16 + col;
    half8 t;
#pragma unroll
    for (int j = 0; j < 8; ++j) {
        int k = kf * 32 + kq * 8 + j;
        t[j] = (k < KIN) ? (_Float16)wih[n * KIN + k] : (_Float16)0.f;
    }
    *((half8*)wsB + idx) = t;
}

// ---------------------------------------------------------------------------
// Fused GRU, 2 sequences per block (128 blocks x 192 threads):
//   wave 0 (consumer): runs seq A=2b and seq B=2b+1 INTERLEAVED in one wave.
//       While seq A's h-broadcast (LDS write->8x ds_read_b128) is in flight,
//       seq B's 96 v_dot2_f32_f16 issue, and vice versa — converts the
//       ~150 cy LDS turnaround + tail stalls of each seq into useful issue
//       of the other. Per-seq math identical to round 4 (bit-compat).
//   waves 1,2 (producers): one per sequence, round-4 producer verbatim:
//       72 MFMA per chunk with pre-packed fp16 B-frags from d_ws, fp32 park
//       in igb[seq] (stride 196, conflict-free).
// ---------------------------------------------------------------------------
__global__ __launch_bounds__(192, 1) void gru_fused(
        const float* __restrict__ x,
        const _Float16* __restrict__ wsB,
        const float* __restrict__ whh,
        const float* __restrict__ bias,
        const float* __restrict__ bias_n,
        const float* __restrict__ wout,
        const float* __restrict__ outb,
        float* __restrict__ out)
{
    __shared__ float igb[2][2][CH][IGS];              // [seq][buf][t][gate] ~100 KB
    __shared__ __align__(16) _Float16 hs[2][HH];      // per-seq h broadcast

    const int tid  = threadIdx.x;
    const int lane = tid & 63;
    const int wid  = tid >> 6;
    const int b0   = 2 * blockIdx.x;

    if (wid >= 1) {
        // ------------------------- producer waves -------------------------
        const int seq = wid - 1;                      // wave1 -> seq A, wave2 -> seq B
        const int col = lane & 15;    // m (timestep row) for A, n for B/D
        const int kq  = lane >> 4;    // 0..3
        float bv[12];
#pragma unroll
        for (int nt = 0; nt < 12; ++nt) bv[nt] = bias[nt * 16 + col];

        const float* xb    = x + (size_t)(b0 + seq) * TT * KIN;
        const half8* bfrag = (const half8*)wsB + lane;   // + (nt*6+kf)*64

        auto produce = [&](int c, int buf) {
            const float* xr = xb + (size_t)(c * CH + col) * KIN + kq * 8;
            half8 af[6];
#pragma unroll
            for (int kf = 0; kf < 5; ++kf) {          // k <= 158: unconditional
                v2f a0 = *(const v2f*)(xr + kf * 32 + 0);
                v2f a1 = *(const v2f*)(xr + kf * 32 + 2);
                v2f a2 = *(const v2f*)(xr + kf * 32 + 4);
                v2f a3 = *(const v2f*)(xr + kf * 32 + 6);
                half8 t;
                t[0] = (_Float16)a0.x; t[1] = (_Float16)a0.y;
                t[2] = (_Float16)a1.x; t[3] = (_Float16)a1.y;
                t[4] = (_Float16)a2.x; t[5] = (_Float16)a2.y;
                t[6] = (_Float16)a3.x; t[7] = (_Float16)a3.y;
                af[kf] = t;
            }
            {                                         // kf = 5: guard k > 180
                v2f z2; z2.x = 0.f; z2.y = 0.f;
                half8 t;
#pragma unroll
                for (int j = 0; j < 4; ++j) {
                    int k = 160 + kq * 8 + 2 * j;
                    v2f a = (k <= 180) ? *(const v2f*)(xr + 160 + 2 * j) : z2;
                    t[2 * j]     = (_Float16)a.x;
                    t[2 * j + 1] = (_Float16)a.y;
                }
                af[5] = t;
            }
#pragma unroll
            for (int nt = 0; nt < 12; ++nt) {
                const half8* bp = bfrag + (size_t)nt * 6 * 64;
                half8 bq0 = bp[0 * 64], bq1 = bp[1 * 64], bq2 = bp[2 * 64];
                half8 bq3 = bp[3 * 64], bq4 = bp[4 * 64], bq5 = bp[5 * 64];
                f32x4 c4 = {bv[nt], bv[nt], bv[nt], bv[nt]};
                c4 = __builtin_amdgcn_mfma_f32_16x16x32_f16(af[0], bq0, c4, 0, 0, 0);
                c4 = __builtin_amdgcn_mfma_f32_16x16x32_f16(af[1], bq1, c4, 0, 0, 0);
                c4 = __builtin_amdgcn_mfma_f32_16x16x32_f16(af[2], bq2, c4, 0, 0, 0);
                c4 = __builtin_amdgcn_mfma_f32_16x16x32_f16(af[3], bq3, c4, 0, 0, 0);
                c4 = __builtin_amdgcn_mfma_f32_16x16x32_f16(af[4], bq4, c4, 0, 0, 0);
                c4 = __builtin_amdgcn_mfma_f32_16x16x32_f16(af[5], bq5, c4, 0, 0, 0);
                // D layout: row = kq*4 + r (timestep), col = nt*16 + col (gate)
                float* dst = &igb[seq][buf][kq * 4][nt * 16 + col];
#pragma unroll
                for (int r = 0; r < 4; ++r) dst[r * IGS] = c4[r];
            }
        };

        produce(0, 0);
        __syncthreads();                              // chunk 0 ready
        for (int c = 0; c < NC; ++c) {
            if (c + 1 < NC) produce(c + 1, (c + 1) & 1);
            __syncthreads();                          // chunk c consumed / c+1 ready
        }
    } else {
        // ------------------------- consumer wave --------------------------
        const int i = lane;                           // owns h_i and gate rows i
        // W_hh rows i, 64+i, 128+i as fp16 half2: 96 VGPRs (shared by both seqs)
        h2v wr[32], wz[32], wn[32];
        {
            const v2f* pr = (const v2f*)(whh + (size_t)(0 * HH + i) * HH);
            const v2f* pz = (const v2f*)(whh + (size_t)(1 * HH + i) * HH);
            const v2f* pn = (const v2f*)(whh + (size_t)(2 * HH + i) * HH);
#pragma unroll
            for (int k = 0; k < 32; ++k) {
                v2f a = pr[k], c2 = pz[k], d2 = pn[k];
                h2v t;
                t[0] = (_Float16)a.x;  t[1] = (_Float16)a.y;  wr[k] = t;
                t[0] = (_Float16)c2.x; t[1] = (_Float16)c2.y; wz[k] = t;
                t[0] = (_Float16)d2.x; t[1] = (_Float16)d2.y; wn[k] = t;
            }
        }
        const float bn = bias_n[i];
        float hA = 0.f, hB = 0.f;
        hs[0][i] = (_Float16)0.f;
        hs[1][i] = (_Float16)0.f;

        __syncthreads();                              // chunk 0 ready

        // one GRU step for one sequence; reload of the h-broadcast is issued
        // at the end so its LDS flight hides under the OTHER seq's dots.
        auto dostep = [&](half8* hv, float& h, _Float16* hsrow,
                          float& cr, float& cz, float& cn, const float* ignext) {
            float r0 = 0.f, r1 = 0.f, z0 = 0.f, z1 = 0.f, n0 = 0.f, n1 = 0.f;
#pragma unroll
            for (int q = 0; q < 8; ++q) {
                half8 hv8 = hv[q];
                h2v h0 = __builtin_shufflevector(hv8, hv8, 0, 1);
                h2v h1 = __builtin_shufflevector(hv8, hv8, 2, 3);
                h2v h2_ = __builtin_shufflevector(hv8, hv8, 4, 5);
                h2v h3 = __builtin_shufflevector(hv8, hv8, 6, 7);
                r0 = dot2(wr[4 * q + 0], h0, r0);
                z0 = dot2(wz[4 * q + 0], h0, z0);
                n0 = dot2(wn[4 * q + 0], h0, n0);
                r1 = dot2(wr[4 * q + 1], h1, r1);
                z1 = dot2(wz[4 * q + 1], h1, z1);
                n1 = dot2(wn[4 * q + 1], h1, n1);
                r0 = dot2(wr[4 * q + 2], h2_, r0);
                z0 = dot2(wz[4 * q + 2], h2_, z0);
                n0 = dot2(wn[4 * q + 2], h2_, n0);
                r1 = dot2(wr[4 * q + 3], h3, r1);
                z1 = dot2(wz[4 * q + 3], h3, z1);
                n1 = dot2(wn[4 * q + 3], h3, n1);
            }
            float vr = cr, vz = cz, vn = cn;
            // branch-free prefetch (wrap to row 0 at lt=15; discarded at chunk edge)
            cr = ignext[i]; cz = ignext[64 + i]; cn = ignext[128 + i];
            // gate tail: v_rcp_f32 instead of IEEE division (~1 ulp)
            float r  = __builtin_amdgcn_rcpf(1.f + __expf(-(vr + r0 + r1)));
            float z  = __builtin_amdgcn_rcpf(1.f + __expf(-(vz + z0 + z1)));
            float e  = __expf(2.f * (vn + r * ((n0 + n1) + bn)));   // tanh
            float nn = 1.f - 2.f * __builtin_amdgcn_rcpf(e + 1.f);
            h = nn + z * (h - nn);
            __builtin_amdgcn_wave_barrier();          // all hv reads precede write
            hsrow[i] = (_Float16)h;
            __builtin_amdgcn_wave_barrier();          // write ordered before reload
#pragma unroll
            for (int q = 0; q < 8; ++q) hv[q] = ((const half8*)hsrow)[q];
            // pin the 8 reloads here so their flight covers the other seq's dots
            __builtin_amdgcn_sched_group_barrier(0x100 /*DS_READ*/, 8, 0);
        };

        half8 vA[8], vB[8];
#pragma unroll
        for (int q = 0; q < 8; ++q) {                 // initial broadcast (zeros)
            vA[q] = ((const half8*)hs[0])[q];
            vB[q] = ((const half8*)hs[1])[q];
        }

        for (int c = 0; c < NC; ++c) {
            const float* igA = &igb[0][c & 1][0][0];
            const float* igB = &igb[1][c & 1][0][0];
            float pAr = igA[i], pAz = igA[64 + i], pAn = igA[128 + i];
            float pBr = igB[i], pBz = igB[64 + i], pBn = igB[128 + i];
#pragma unroll 8
            for (int lt = 0; lt < CH; ++lt) {
                const float* nxA = igA + ((lt + 1) & 15) * IGS;
                const float* nxB = igB + ((lt + 1) & 15) * IGS;
                dostep(vA, hA, hs[0], pAr, pAz, pAn, nxA);
                dostep(vB, hB, hs[1], pBr, pBz, pBn, nxB);
            }
            __syncthreads();                          // hand buffers to producers
        }

        // readout for both sequences: sigmoid(h . w_out^T + out_bias)
        float s0A = wout[i] * hA, s1A = wout[HH + i] * hA;
        float s0B = wout[i] * hB, s1B = wout[HH + i] * hB;
#pragma unroll
        for (int off = 32; off > 0; off >>= 1) {
            s0A += __shfl_down(s0A, off);
            s1A += __shfl_down(s1A, off);
            s0B += __shfl_down(s0B, off);
            s1B += __shfl_down(s1B, off);
        }
        if (i == 0) {
            out[2 * b0 + 0] = __builtin_amdgcn_rcpf(1.f + __expf(-(s0A + outb[0])));
            out[2 * b0 + 1] = __builtin_amdgcn_rcpf(1.f + __expf(-(s1A + outb[1])));
            out[2 * b0 + 2] = __builtin_amdgcn_rcpf(1.f + __expf(-(s0B + outb[0])));
            out[2 * b0 + 3] = __builtin_amdgcn_rcpf(1.f + __expf(-(s1B + outb[1])));
        }
    }
}

extern "C" void kernel_launch(void* const* d_in, const int* in_sizes, int n_in,
                              void* d_out, int out_size, void* d_ws, size_t ws_size,
                              hipStream_t stream) {
    const float* x     = (const float*)d_in[0];
    const float* wih   = (const float*)d_in[1];
    const float* whh   = (const float*)d_in[2];
    const float* bias  = (const float*)d_in[3];
    const float* biasn = (const float*)d_in[4];
    const float* wout  = (const float*)d_in[5];
    const float* outb  = (const float*)d_in[6];
    float* out = (float*)d_out;

    if (ws_size < WS_NEEDED) {
        hipMemsetAsync(d_out, 0xFF, (size_t)out_size * sizeof(float), stream);
        return;
    }
    _Float16* wsB = (_Float16*)d_ws;

    pack_wih<<<(NFRAG + 255) / 256, 256, 0, stream>>>(wih, wsB);
    gru_fused<<<NBLK, 192, 0, stream>>>(x, wsB, whh, bias, biasn, wout, outb, out);
}